// Round 2
// baseline (385.595 us; speedup 1.0000x reference)
//
#include <hip/hip_runtime.h>
#include <stdint.h>

#define NB 16
#define NC 256
#define NH 48
#define NW 160
#define HW (NH*NW)        // 7680
#define NP (NB*HW)        // 122880

static __device__ __forceinline__ unsigned short f2bf(float f){
  union { float f; uint32_t u; } v; v.f = f;
  uint32_t u = v.u;
  uint32_t r = (u + 0x7FFFu + ((u >> 16) & 1u)) >> 16;
  return (unsigned short)r;
}
static __device__ __forceinline__ float bf2f(unsigned short h){
  union { float f; uint32_t u; } v; v.u = ((uint32_t)h) << 16; return v.f;
}

// ---------------- KW: w_ext (256x257 fp32) -> Wb (256x256 bf16, col 1..256) --
__global__ __launch_bounds__(256) void kw_conv(const float* __restrict__ w_ext,
                                               unsigned short* __restrict__ Wb){
  int idx = blockIdx.x * 256 + threadIdx.x;   // 65536 total
  int o = idx >> 8, c = idx & 255;
  Wb[idx] = f2bf(w_ext[o * 257 + 1 + c]);
}

// ---------------- KA: transpose+cvt x -> xT[p][c] bf16, plus conv-as-GEMM T --
#define TRS 132   // 128 + 4 pad (ushort units); row = 264 B, 8B aligned
__global__ __launch_bounds__(256) void ka_stage(
    const float* __restrict__ x, const float* __restrict__ w_disp,
    unsigned short* __restrict__ xT, float* __restrict__ T)
{
  __shared__ __align__(16) unsigned short tr[128 * TRS];
  int t = threadIdx.x;
  int p0 = blockIdx.x * 128;          // 960 blocks; tiles never cross batch (7680 = 60*128)
  int b  = p0 / HW;
  int hw0 = p0 - b * HW;
  int l32 = t & 31;
  int cg  = t >> 5;
  int pl   = t & 127;
  int half = t >> 7;

  float acc[9];
  #pragma unroll
  for (int k = 0; k < 9; ++k) acc[k] = 0.f;

  for (int h = 0; h < 2; ++h){
    __syncthreads();
    // phase 1: coalesced float4 read along p, cvt, LDS-transposed store
    for (int it = 0; it < 16; ++it){
      int cl = it * 8 + cg;                // local c 0..127
      int c  = h * 128 + cl;
      const float* src = x + ((size_t)(b * NC + c)) * HW + hw0 + l32 * 4;
      float4 v = *(const float4*)src;
      int p = l32 * 4;
      tr[(p + 0) * TRS + cl] = f2bf(v.x);
      tr[(p + 1) * TRS + cl] = f2bf(v.y);
      tr[(p + 2) * TRS + cl] = f2bf(v.z);
      tr[(p + 3) * TRS + cl] = f2bf(v.w);
    }
    __syncthreads();
    // phase 2: coalesced bf16 write of xT[p][c]
    for (int it = 0; it < 16; ++it){
      int idx = it * 256 + t;              // 0..4095
      int p  = idx >> 5;
      int c4 = (idx & 31) * 4;
      ushort4 v = *(const ushort4*)&tr[p * TRS + c4];
      *(ushort4*)(xT + ((size_t)(p0 + p)) * 256 + h * 128 + c4) = v;
    }
    // phase 3: conv as per-pixel 9-tap dot over channels; all 256 threads
    {
      int clbase = half * 64;
      for (int cl = clbase; cl < clbase + 64; cl += 4){
        ushort4 v = *(const ushort4*)&tr[pl * TRS + cl];
        float f0 = bf2f(v.x), f1 = bf2f(v.y), f2 = bf2f(v.z), f3 = bf2f(v.w);
        const float* wd = w_disp + (h * 128 + cl) * 9;   // uniform -> scalar loads
        #pragma unroll
        for (int k = 0; k < 9; ++k)
          acc[k] += f0 * wd[k] + f1 * wd[9 + k] + f2 * wd[18 + k] + f3 * wd[27 + k];
      }
    }
  }
  // cross-half reduction via LDS, then store T
  __syncthreads();
  float* red = (float*)tr;
  if (half == 1){
    #pragma unroll
    for (int k = 0; k < 9; ++k) red[pl * 9 + k] = acc[k];
  }
  __syncthreads();
  if (half == 0){
    #pragma unroll
    for (int k = 0; k < 9; ++k)
      T[(size_t)k * NP + p0 + pl] = acc[k] + red[pl * 9 + k];
  }
}

// ---------------- KB: U[o][p] = sum_c Wb[o][c] * xT[p][c]  (bf16 MFMA GEMM) --
typedef __attribute__((ext_vector_type(8))) short bf16x8;
typedef __attribute__((ext_vector_type(4))) float f32x4;

__global__ __launch_bounds__(256) void kb_gemm(
    const unsigned short* __restrict__ Wb,   // [256][256] k-contig
    const unsigned short* __restrict__ xT,   // [NP][256]  k-contig
    unsigned short* __restrict__ U)          // [NB*NC][HW] bf16
{
  __shared__ __align__(16) unsigned short smem[16 * 512];
  int bx = blockIdx.x;                 // 1920 = 16 b * 2 mt * 60 nt
  int b   = bx / 120;
  int rem = bx - b * 120;
  int mt  = rem & 1;
  int nt  = rem >> 1;

  int tid  = threadIdx.x;
  int lane = tid & 63;
  int w    = tid >> 6;                 // wave 0..3
  int wm = w & 1, wn = w >> 1;
  int l15 = lane & 15;
  int lq  = lane >> 4;

  f32x4 zero = {0.f, 0.f, 0.f, 0.f};
  f32x4 acc[4][4];
  #pragma unroll
  for (int mi = 0; mi < 4; ++mi)
    #pragma unroll
    for (int ni = 0; ni < 4; ++ni) acc[mi][ni] = zero;

  for (int ks = 0; ks < 8; ++ks){
    __syncthreads();
    #pragma unroll
    for (int i = 0; i < 4; ++i){
      int u = w * 4 + i;
      const unsigned short* src;
      if (u < 8){
        int m = mt * 128 + u * 16 + l15;
        src = Wb + ((size_t)m * 256 + ks * 32 + lq * 8);
      } else {
        int n = nt * 128 + (u - 8) * 16 + l15;
        src = xT + ((size_t)(b * HW + n)) * 256 + ks * 32 + lq * 8;
      }
      bf16x8 v = *(const bf16x8*)src;                 // 16B global load
      *(bf16x8*)(smem + u * 512 + lane * 8) = v;      // fragment-ordered: lane*16B
    }
    __syncthreads();
    bf16x8 af[4], bg[4];
    #pragma unroll
    for (int mi = 0; mi < 4; ++mi)
      af[mi] = *(const bf16x8*)(smem + (wm * 4 + mi) * 512 + lane * 8);
    #pragma unroll
    for (int ni = 0; ni < 4; ++ni)
      bg[ni] = *(const bf16x8*)(smem + (8 + wn * 4 + ni) * 512 + lane * 8);
    #pragma unroll
    for (int mi = 0; mi < 4; ++mi)
      #pragma unroll
      for (int ni = 0; ni < 4; ++ni)
        acc[mi][ni] = __builtin_amdgcn_mfma_f32_16x16x32_bf16(af[mi], bg[ni], acc[mi][ni], 0, 0, 0);
  }

  // epilogue: C/D layout col=lane&15 (n), row=(lane>>4)*4+r (m)
  #pragma unroll
  for (int mi = 0; mi < 4; ++mi){
    #pragma unroll
    for (int ni = 0; ni < 4; ++ni){
      int o  = mt * 128 + wm * 64 + mi * 16 + lq * 4;
      int hw = nt * 128 + wn * 64 + ni * 16 + l15;
      size_t base = ((size_t)(b * NC + o)) * HW + hw;
      #pragma unroll
      for (int r = 0; r < 4; ++r)
        U[base + (size_t)r * HW] = f2bf(acc[mi][ni][r]);
    }
  }
}

// ---------------- KP: per-pixel grid params (wy, dlerp, off0, off1) ---------
__global__ __launch_bounds__(256) void kp_grid(
    const float* __restrict__ P2, const float* __restrict__ b_disp,
    const float* __restrict__ T, float4* __restrict__ pre)
{
  int p = blockIdx.x * 256 + threadIdx.x;   // 0..122879
  int b  = p / HW;
  int hw = p - b * HW;
  int y  = hw / NW;
  int xx = hw - y * NW;

  float d = 0.f;
  #pragma unroll
  for (int ky = 0; ky < 3; ++ky){
    int yy2 = y + ky - 1;
    if (yy2 < 0 || yy2 >= NH) continue;
    #pragma unroll
    for (int kx = 0; kx < 3; ++kx){
      int xx2 = xx + kx - 1;
      if (xx2 < 0 || xx2 >= NW) continue;
      d += T[(size_t)(ky * 3 + kx) * NP + b * HW + yy2 * NW + xx2];
    }
  }
  float th = tanhf(d + b_disp[0]);

  float fy = P2[b * 12 + 5] * 0.0625f;
  float cy = P2[b * 12 + 6] * 0.0625f;
  float Ty = P2[b * 12 + 7] * 0.0625f;

  float ysb   = fmaxf(1.535f * ((float)y - cy) / 1.765f, 0.f) * (1.f / 24.f);
  float ybase = -1.f + (float)y * (2.f / 47.f);
  float gy = ybase + ysb + 0.1f * th;
  float iy = fminf(fmaxf((gy + 1.f) * 0.5f * 47.f, 0.f), 47.f);
  float fiy0 = floorf(iy);
  float wy = iy - fiy0;
  int iy0 = (int)fiy0;
  int iy1 = min(iy0 + 1, 47);

  float inv_den = 1.f / (fabsf(fy * 1.65f + Ty) + 1e-10f);
  float dr0 = fmaxf(fy * 0.54f * ((float)iy0 - cy) * inv_den, 0.f);
  float dr1 = fmaxf(fy * 0.54f * ((float)iy1 - cy) * inv_den, 0.f);
  float dlerp = (1.f - wy) * dr0 + wy * dr1;

  float4 pr;
  pr.x = wy; pr.y = dlerp;
  pr.z = __int_as_float(iy0 * NW + xx);
  pr.w = __int_as_float(iy1 * NW + xx);
  pre[p] = pr;
}

// ---------------- KC: lerp + matvec-residual ReLU, split over channel groups
__global__ __launch_bounds__(256) void kc_epilogue(
    const float* __restrict__ x, const float* __restrict__ w_ext,
    const float* __restrict__ b_ext, const float* __restrict__ alpha,
    const unsigned short* __restrict__ U, const float4* __restrict__ pre,
    float* __restrict__ out)
{
  int bx = blockIdx.x;            // 3840 = 480 ptile * 8 cg
  int ptile = bx >> 3;
  int cg    = bx & 7;
  int p = ptile * 256 + threadIdx.x;
  int b  = p / HW;
  int hw = p - b * HW;

  float4 pr = pre[p];
  float wy    = pr.x;
  float dlerp = pr.y;
  int off0 = __float_as_int(pr.z);
  int off1 = __float_as_int(pr.w);
  float w1 = 1.f - wy;
  float al = alpha[0];

  size_t base0 = (size_t)(b * NC) * HW;
  const unsigned short* Ub = U + base0;
  const float* xb = x + base0 + hw;
  float* ob = out + base0 + hw;

  int o0 = cg * 32;
  #pragma unroll 4
  for (int o = o0; o < o0 + 32; ++o){
    float u0 = bf2f(Ub[(size_t)o * HW + off0]);
    float u1 = bf2f(Ub[(size_t)o * HW + off1]);
    float val = w1 * u0 + wy * u1 + w_ext[o * 257] * dlerp + b_ext[o];
    float r = xb[(size_t)o * HW] + al * val;
    ob[(size_t)o * HW] = fmaxf(r, 0.f);
  }
}

// ---------------------------------------------------------------------------
extern "C" void kernel_launch(void* const* d_in, const int* in_sizes, int n_in,
                              void* d_out, int out_size, void* d_ws, size_t ws_size,
                              hipStream_t stream) {
  const float* features = (const float*)d_in[0];
  const float* P2       = (const float*)d_in[1];
  const float* w_disp   = (const float*)d_in[2];
  const float* b_disp   = (const float*)d_in[3];
  const float* w_ext    = (const float*)d_in[4];
  const float* b_ext    = (const float*)d_in[5];
  const float* alpha    = (const float*)d_in[6];
  float* out = (float*)d_out;

  char* ws = (char*)d_ws;
  const size_t xT_bytes = (size_t)NP * 256 * 2;   // 62,914,560
  unsigned short* xT = (unsigned short*)ws;
  unsigned short* U  = (unsigned short*)(ws + xT_bytes);
  float* T           = (float*)(ws + 2 * xT_bytes);
  unsigned short* Wb = (unsigned short*)(ws + 2 * xT_bytes + (size_t)9 * NP * 4);
  // pre aliases xT: KB (last reader of xT) completes before KP writes pre
  float4* pre        = (float4*)ws;

  hipLaunchKernelGGL(kw_conv,     dim3(256),  dim3(256), 0, stream, w_ext, Wb);
  hipLaunchKernelGGL(ka_stage,    dim3(960),  dim3(256), 0, stream, features, w_disp, xT, T);
  hipLaunchKernelGGL(kb_gemm,     dim3(1920), dim3(256), 0, stream, Wb, xT, U);
  hipLaunchKernelGGL(kp_grid,     dim3(480),  dim3(256), 0, stream, P2, b_disp, T, pre);
  hipLaunchKernelGGL(kc_epilogue, dim3(3840), dim3(256), 0, stream,
                     features, w_ext, b_ext, alpha, U, pre, out);
}

// Round 3
// 321.543 us; speedup vs baseline: 1.1992x; 1.1992x over previous
//
#include <hip/hip_runtime.h>
#include <stdint.h>

#define NB 16
#define NC 256
#define NH 48
#define NW 160
#define HW (NH*NW)        // 7680
#define NP (NB*HW)        // 122880

static __device__ __forceinline__ unsigned short f2bf(float f){
  union { float f; uint32_t u; } v; v.f = f;
  uint32_t u = v.u;
  uint32_t r = (u + 0x7FFFu + ((u >> 16) & 1u)) >> 16;
  return (unsigned short)r;
}
static __device__ __forceinline__ float bf2f(unsigned short h){
  union { float f; uint32_t u; } v; v.u = ((uint32_t)h) << 16; return v.f;
}

// ---- KW: Wb[o][c] = bf16(w_ext[o][1+c]);  Wtap[m][c] = bf16(w_disp[c*9+m]) --
__global__ __launch_bounds__(256) void kw_conv(const float* __restrict__ w_ext,
                                               const float* __restrict__ w_disp,
                                               unsigned short* __restrict__ Wb,
                                               unsigned short* __restrict__ Wtap){
  if (blockIdx.x < 256){
    int idx = blockIdx.x * 256 + threadIdx.x;
    int o = idx >> 8, c = idx & 255;
    Wb[idx] = f2bf(w_ext[o * 257 + 1 + c]);
  } else {
    int c = threadIdx.x;
    #pragma unroll
    for (int m = 0; m < 16; ++m){
      float v = (m < 9) ? w_disp[c * 9 + m] : 0.f;
      Wtap[m * 256 + c] = f2bf(v);
    }
  }
}

// ---- KB: fused transpose-stage + GEMM.  U[o][p] = sum_c Wb[o][c]*x[c][p],
//          T[k][p] = sum_c Wtap[k][c]*x[c][p]  (conv taps, wave 0 only) ------
typedef __attribute__((ext_vector_type(8))) short bf16x8;
typedef __attribute__((ext_vector_type(4))) float f32x4;

__global__ __launch_bounds__(256) void kb_gemm(
    const float* __restrict__ x,             // [NB][NC][HW] fp32
    const unsigned short* __restrict__ Wb,   // [256][256] bf16 k-contig
    const unsigned short* __restrict__ Wtap, // [16][256]  bf16 k-contig
    unsigned short* __restrict__ U,          // [NB*NC][HW] bf16
    float* __restrict__ T)                   // [9][NP] fp32
{
  // B-tile LDS, fragment-ordered: 4 units (16n x 32k), unit u holds n=u*16+l15
  __shared__ __align__(16) unsigned short smem[4 * 512];
  int bx = blockIdx.x;            // 1920 = 16 b * 120 nt
  int b  = bx / 120;
  int nt = bx - b * 120;
  int p0 = nt * 64;               // hw offset within image (64 | 7680)

  int tid  = threadIdx.x;
  int lane = tid & 63;
  int w    = tid >> 6;            // wave 0..3 ; wm = w (m-quarter of 64)
  int l15 = lane & 15;
  int lq  = lane >> 4;

  // staging role: thread covers (n = tid&63, kq = tid>>6); 8 floats k-strided
  int sn  = tid & 63;
  int skq = tid >> 6;
  const float* xbase = x + ((size_t)b * NC) * HW + p0 + sn;
  unsigned short* swr = smem + (sn >> 4) * 512 + ((sn & 15) + skq * 16) * 8;

  f32x4 zero = {0.f, 0.f, 0.f, 0.f};
  f32x4 acc[4][4];
  f32x4 acct[4];
  #pragma unroll
  for (int mi = 0; mi < 4; ++mi){
    acct[mi] = zero;
    #pragma unroll
    for (int ni = 0; ni < 4; ++ni) acc[mi][ni] = zero;
  }

  for (int ks = 0; ks < 8; ++ks){
    __syncthreads();
    {
      int c0 = ks * 32 + skq * 8;
      const float* src = xbase + (size_t)c0 * HW;
      unsigned short h[8];
      #pragma unroll
      for (int j = 0; j < 8; ++j)
        h[j] = f2bf(src[(size_t)j * HW]);   // each j: 64-lane coalesced 256B
      *(bf16x8*)swr = *(bf16x8*)h;           // fragment-ordered 16B LDS store
    }
    __syncthreads();

    bf16x8 af[4], bg[4];
    #pragma unroll
    for (int mi = 0; mi < 4; ++mi){
      int m = w * 64 + mi * 16 + l15;
      af[mi] = *(const bf16x8*)(Wb + (size_t)m * 256 + ks * 32 + lq * 8);
    }
    #pragma unroll
    for (int ni = 0; ni < 4; ++ni)
      bg[ni] = *(const bf16x8*)(smem + ni * 512 + lane * 8);

    #pragma unroll
    for (int mi = 0; mi < 4; ++mi)
      #pragma unroll
      for (int ni = 0; ni < 4; ++ni)
        acc[mi][ni] = __builtin_amdgcn_mfma_f32_16x16x32_bf16(af[mi], bg[ni], acc[mi][ni], 0, 0, 0);

    if (w == 0){
      bf16x8 at = *(const bf16x8*)(Wtap + (size_t)l15 * 256 + ks * 32 + lq * 8);
      #pragma unroll
      for (int ni = 0; ni < 4; ++ni)
        acct[ni] = __builtin_amdgcn_mfma_f32_16x16x32_bf16(at, bg[ni], acct[ni], 0, 0, 0);
    }
  }

  // epilogue U: C/D layout col=lane&15 (n), row=lq*4+r (m)
  #pragma unroll
  for (int mi = 0; mi < 4; ++mi){
    #pragma unroll
    for (int ni = 0; ni < 4; ++ni){
      int o = w * 64 + mi * 16 + lq * 4;
      int n = ni * 16 + l15;
      size_t base = ((size_t)(b * NC + o)) * HW + p0 + n;
      #pragma unroll
      for (int r = 0; r < 4; ++r)
        U[base + (size_t)r * HW] = f2bf(acc[mi][ni][r]);
    }
  }
  // epilogue T (wave 0): row = lq*4+r = tap index, keep rows 0..8
  if (w == 0){
    #pragma unroll
    for (int ni = 0; ni < 4; ++ni){
      int n = ni * 16 + l15;
      #pragma unroll
      for (int r = 0; r < 4; ++r){
        int k = lq * 4 + r;
        if (k < 9)
          T[(size_t)k * NP + (size_t)b * HW + p0 + n] = acct[ni][r];
      }
    }
  }
}

// ---- KP: per-pixel grid params (wy, dlerp, off0, off1) ----------------------
__global__ __launch_bounds__(256) void kp_grid(
    const float* __restrict__ P2, const float* __restrict__ b_disp,
    const float* __restrict__ T, float4* __restrict__ pre)
{
  int p = blockIdx.x * 256 + threadIdx.x;   // 0..122879
  int b  = p / HW;
  int hw = p - b * HW;
  int y  = hw / NW;
  int xx = hw - y * NW;

  float d = 0.f;
  #pragma unroll
  for (int ky = 0; ky < 3; ++ky){
    int yy2 = y + ky - 1;
    if (yy2 < 0 || yy2 >= NH) continue;
    #pragma unroll
    for (int kx = 0; kx < 3; ++kx){
      int xx2 = xx + kx - 1;
      if (xx2 < 0 || xx2 >= NW) continue;
      d += T[(size_t)(ky * 3 + kx) * NP + b * HW + yy2 * NW + xx2];
    }
  }
  float th = tanhf(d + b_disp[0]);

  float fy = P2[b * 12 + 5] * 0.0625f;
  float cy = P2[b * 12 + 6] * 0.0625f;
  float Ty = P2[b * 12 + 7] * 0.0625f;

  float ysb   = fmaxf(1.535f * ((float)y - cy) / 1.765f, 0.f) * (1.f / 24.f);
  float ybase = -1.f + (float)y * (2.f / 47.f);
  float gy = ybase + ysb + 0.1f * th;
  float iy = fminf(fmaxf((gy + 1.f) * 0.5f * 47.f, 0.f), 47.f);
  float fiy0 = floorf(iy);
  float wy = iy - fiy0;
  int iy0 = (int)fiy0;
  int iy1 = min(iy0 + 1, 47);

  float inv_den = 1.f / (fabsf(fy * 1.65f + Ty) + 1e-10f);
  float dr0 = fmaxf(fy * 0.54f * ((float)iy0 - cy) * inv_den, 0.f);
  float dr1 = fmaxf(fy * 0.54f * ((float)iy1 - cy) * inv_den, 0.f);
  float dlerp = (1.f - wy) * dr0 + wy * dr1;

  float4 pr;
  pr.x = wy; pr.y = dlerp;
  pr.z = __int_as_float(iy0 * NW + xx);
  pr.w = __int_as_float(iy1 * NW + xx);
  pre[p] = pr;
}

// ---- KC: lerp + matvec-residual ReLU, split over 8 channel groups ----------
__global__ __launch_bounds__(256) void kc_epilogue(
    const float* __restrict__ x, const float* __restrict__ w_ext,
    const float* __restrict__ b_ext, const float* __restrict__ alpha,
    const unsigned short* __restrict__ U, const float4* __restrict__ pre,
    float* __restrict__ out)
{
  int bx = blockIdx.x;            // 3840 = 480 ptile * 8 cg
  int ptile = bx >> 3;
  int cg    = bx & 7;
  int p = ptile * 256 + threadIdx.x;
  int b  = p / HW;
  int hw = p - b * HW;

  float4 pr = pre[p];
  float wy    = pr.x;
  float dlerp = pr.y;
  int off0 = __float_as_int(pr.z);
  int off1 = __float_as_int(pr.w);
  float w1 = 1.f - wy;
  float al = alpha[0];

  size_t base0 = (size_t)(b * NC) * HW;
  const unsigned short* Ub = U + base0;
  const float* xb = x + base0 + hw;
  float* ob = out + base0 + hw;

  int o0 = cg * 32;
  #pragma unroll 4
  for (int o = o0; o < o0 + 32; ++o){
    float u0 = bf2f(Ub[(size_t)o * HW + off0]);
    float u1 = bf2f(Ub[(size_t)o * HW + off1]);
    float val = w1 * u0 + wy * u1 + w_ext[o * 257] * dlerp + b_ext[o];
    float r = xb[(size_t)o * HW] + al * val;
    ob[(size_t)o * HW] = fmaxf(r, 0.f);
  }
}

// ---------------------------------------------------------------------------
extern "C" void kernel_launch(void* const* d_in, const int* in_sizes, int n_in,
                              void* d_out, int out_size, void* d_ws, size_t ws_size,
                              hipStream_t stream) {
  const float* features = (const float*)d_in[0];
  const float* P2       = (const float*)d_in[1];
  const float* w_disp   = (const float*)d_in[2];
  const float* b_disp   = (const float*)d_in[3];
  const float* w_ext    = (const float*)d_in[4];
  const float* b_ext    = (const float*)d_in[5];
  const float* alpha    = (const float*)d_in[6];
  float* out = (float*)d_out;

  char* ws = (char*)d_ws;
  const size_t U_bytes   = (size_t)NP * 256 * 2;    // 62,914,560
  const size_t T_bytes   = (size_t)9 * NP * 4;      //  4,423,680
  const size_t pre_bytes = (size_t)NP * 16;         //  1,966,080
  unsigned short* U    = (unsigned short*)ws;
  float*          T    = (float*)(ws + U_bytes);
  float4*         pre  = (float4*)(ws + U_bytes + T_bytes);
  unsigned short* Wb   = (unsigned short*)(ws + U_bytes + T_bytes + pre_bytes);
  unsigned short* Wtap = Wb + 256 * 256;

  hipLaunchKernelGGL(kw_conv,     dim3(257),  dim3(256), 0, stream, w_ext, w_disp, Wb, Wtap);
  hipLaunchKernelGGL(kb_gemm,     dim3(1920), dim3(256), 0, stream, features, Wb, Wtap, U, T);
  hipLaunchKernelGGL(kp_grid,     dim3(480),  dim3(256), 0, stream, P2, b_disp, T, pre);
  hipLaunchKernelGGL(kc_epilogue, dim3(3840), dim3(256), 0, stream,
                     features, w_ext, b_ext, alpha, U, pre, out);
}